// Round 9
// baseline (1888.939 us; speedup 1.0000x reference)
//
#include <hip/hip_runtime.h>

#define UNROLL _Pragma("unroll")

typedef __attribute__((ext_vector_type(8))) short bf16x8;
typedef __attribute__((ext_vector_type(4))) float f32x4;

__device__ __forceinline__ unsigned short f2bf_rne(float x) {
  unsigned u = __float_as_uint(x);
  unsigned r = (u + 0x7FFFu + ((u >> 16) & 1u)) >> 16;
  return (unsigned short)r;
}

__device__ __forceinline__ float fast_sigmoid(float x) {
  return __builtin_amdgcn_rcpf(1.f + __expf(-x));
}
__device__ __forceinline__ float fast_tanh(float x) {
  return 1.f - 2.f * __builtin_amdgcn_rcpf(__expf(2.f * x) + 1.f);
}

// ---------------- init: reset all 8 mailbox copies (tag=0) ----------------
__global__ void k_init(unsigned long long* hword) {
  int t = threadIdx.x;
  for (int i = t; i < 8192; i += 256) hword[i] = 0ull;  // 8 copies x 2 parities x 512
}

// ---------------- pre-GEMM: pre[step][unit*4+gate] = emb@Wih.T + bih + bhh ----------------
// Teacher forcing: all tokens known -> both LSTMs' input projections are one parallel
// GEMM. grid (16, 8): nt over 2048 gate-rows, mt over 1024 step-rows (mt<4 = encoder
// rows 0..511 from source; mt>=4 = decoder rows 512..1022 from target[0..510]).
__global__ __launch_bounds__(256, 2) void k_pre(
    const int* __restrict__ source, const int* __restrict__ target,
    const float* __restrict__ enc_embed, const float* __restrict__ enc_Wih,
    const float* __restrict__ enc_bih, const float* __restrict__ enc_bhh,
    const float* __restrict__ dec_embed, const float* __restrict__ dec_Wih,
    const float* __restrict__ dec_bih, const float* __restrict__ dec_bhh,
    float* __restrict__ pre) {
  const int nt = blockIdx.x;
  const int mt = blockIdx.y;
  const int phase = mt >> 2;
  const int nbase = nt << 7;
  const int mbase = mt << 7;
  const int tid = threadIdx.x;
  const int l = tid & 63;
  const int q = l >> 4;
  const int cc = l & 15;
  const int W = tid >> 6;
  const int wm = W >> 1, wn = W & 1;

  const float* emb = phase ? dec_embed : enc_embed;
  const float* Wih = phase ? dec_Wih : enc_Wih;
  const float* bih = phase ? dec_bih : enc_bih;
  const float* bhh = phase ? dec_bhh : enc_bhh;

  __shared__ __align__(16) unsigned short Asm[128][40];
  __shared__ __align__(16) unsigned short Bsm[128][40];

  f32x4 acc[4][4];
  f32x4 zero = {0.f, 0.f, 0.f, 0.f};
  UNROLL for (int i = 0; i < 4; ++i) UNROLL for (int j = 0; j < 4; ++j) acc[i][j] = zero;

  const int srow = tid >> 1;
  const int sh = tid & 1;
  const int m = mbase + srow;
  int tok;
  if (phase == 0) {
    tok = source[m];
  } else {
    int rel = m - 512;
    tok = (rel < 511) ? target[rel] : 0;  // row 1023 is a dummy (stores guarded)
  }
  const float* arow = emb + (size_t)tok * 512;
  const float* brow = Wih + (size_t)(nbase + srow) * 512;

  for (int kc = 0; kc < 16; ++kc) {
    // stage A tile (gathered embedding rows, f32 -> bf16)
    {
      const float* ap = arow + (kc << 5) + (sh << 4);
      float av[16];
      *(float4*)&av[0] = *(const float4*)ap;
      *(float4*)&av[4] = *(const float4*)(ap + 4);
      *(float4*)&av[8] = *(const float4*)(ap + 8);
      *(float4*)&av[12] = *(const float4*)(ap + 12);
      unsigned short us[16];
      UNROLL for (int j = 0; j < 16; ++j) us[j] = f2bf_rne(av[j]);
      *(uint4*)&Asm[srow][(sh << 4)] = *(const uint4*)&us[0];
      *(uint4*)&Asm[srow][(sh << 4) + 8] = *(const uint4*)&us[8];
    }
    // stage B tile (Wih rows, f32 -> bf16)
    {
      const float* bp = brow + (kc << 5) + (sh << 4);
      float bv[16];
      *(float4*)&bv[0] = *(const float4*)bp;
      *(float4*)&bv[4] = *(const float4*)(bp + 4);
      *(float4*)&bv[8] = *(const float4*)(bp + 8);
      *(float4*)&bv[12] = *(const float4*)(bp + 12);
      unsigned short us[16];
      UNROLL for (int j = 0; j < 16; ++j) us[j] = f2bf_rne(bv[j]);
      *(uint4*)&Bsm[srow][(sh << 4)] = *(const uint4*)&us[0];
      *(uint4*)&Bsm[srow][(sh << 4) + 8] = *(const uint4*)&us[8];
    }
    __syncthreads();

    bf16x8 af[4], bfr[4];
    UNROLL for (int mi = 0; mi < 4; ++mi)
      af[mi] = *(const bf16x8*)((const char*)Asm + (size_t)((wm << 6) + (mi << 4) + cc) * 80 + (q << 4));
    UNROLL for (int ni = 0; ni < 4; ++ni)
      bfr[ni] = *(const bf16x8*)((const char*)Bsm + (size_t)((wn << 6) + (ni << 4) + cc) * 80 + (q << 4));
    UNROLL for (int mi = 0; mi < 4; ++mi)
      UNROLL for (int ni = 0; ni < 4; ++ni)
        acc[mi][ni] = __builtin_amdgcn_mfma_f32_16x16x32_bf16(af[mi], bfr[ni], acc[mi][ni], 0, 0, 0);

    __syncthreads();
  }

  // epilogue: + (bih+bhh); scatter to pre[m][ (u&511)*4 + gate ]
  float bo[4];
  UNROLL for (int ni = 0; ni < 4; ++ni) {
    int cr = nbase + (wn << 6) + (ni << 4) + cc;
    bo[ni] = bih[cr] + bhh[cr];
  }
  UNROLL for (int mi = 0; mi < 4; ++mi) {
    UNROLL for (int r = 0; r < 4; ++r) {
      int rowb = (wm << 6) + (mi << 4) + (q << 2) + r;  // C/D: col=lane&15, row=(lane>>4)*4+r
      int m2 = mbase + rowb;
      if (phase == 0 || m2 < 1023) {
        UNROLL for (int ni = 0; ni < 4; ++ni) {
          int cr = nbase + (wn << 6) + (ni << 4) + cc;
          pre[(size_t)m2 * 2048 + ((cr & 511) << 2) + (cr >> 9)] = acc[mi][ni][r] + bo[ni];
        }
      }
    }
  }
}

// ---------------- persistent sequential LSTM (enc 512 + dec 511 steps) ----------------
// Round-8 structure; ONLY delta: COALESCED LINE PUBLISH. Each wave drops its
// {tag,h} u64 into LDS hpub[8]; barrier; then ONE rotating wave (wv==S&7)
// publishes the whole block's 8 units x 8 copies in a single 64-lane store:
// lane l -> copy l>>3, unit l&7 => each 8-lane group writes one contiguous
// 64B mailbox line. 8 clean full-line writes per block per step instead of
// 64 scattered 8B sector-RMWs (WRITE_SIZE said each cost a 32B transaction).
// Poll side unchanged: block b polls copy b&7, tags ride in the words,
// parity double-buffer, k_init re-zeroes -> replay safe.
__global__ __launch_bounds__(512, 1) void k_lstm(
    const float* __restrict__ enc_Whh, const float* __restrict__ dec_Whh,
    const float* __restrict__ pre, unsigned long long* hword, unsigned short* hsb) {
  const int blk = blockIdx.x;
  const int tid = threadIdx.x;
  const int lane = tid & 63;
  const int wv = tid >> 6;
  const int U = (blk << 3) + wv;  // global hidden unit
  const int mycopy = blk & 7;

  __shared__ float hsm[2][512];           // parity-split broadcast buffer
  __shared__ unsigned long long hpub[8];  // this block's 8 {tag,h} words

  float c = 0.f;

  for (int phase = 0; phase < 2; ++phase) {
    const float* Whh = phase ? dec_Whh : enc_Whh;

    float whh[4][8];
    UNROLL for (int g = 0; g < 4; ++g) {
      const float* p2 = Whh + (size_t)((g << 9) + U) * 512 + lane;
      UNROLL for (int k = 0; k < 8; ++k) whh[g][k] = p2[k << 6];
    }
    UNROLL for (int g = 0; g < 4; ++g) UNROLL for (int k = 0; k < 8; ++k)
      asm volatile("" : "+v"(whh[g][k]));

    const int T = phase ? 511 : 512;
    for (int t = 0; t < T; ++t) {
      const int S = (phase ? 512 : 0) + t;  // consume state-after-S-steps
      const int par = S & 1;

      // this wave's 4 gate pre-activations (pre = emb@Wih.T + biases), issued
      // before the poll so MALL latency hides under the spin
      float pf = pre[(size_t)S * 2048 + (U << 2) + (lane & 3)];
      asm volatile("" : "+v"(pf));  // don't sink past the poll

      // wave wv polls its 64-unit slice of THIS block's mailbox copy
      if (S > 0) {
        const unsigned long long* hw = hword + (mycopy << 10) + (par << 9) + (wv << 6) + lane;
        unsigned long long w;
        do {
          w = __hip_atomic_load(hw, __ATOMIC_RELAXED, __HIP_MEMORY_SCOPE_AGENT);
        } while (!__all((unsigned)(w >> 32) == (unsigned)S));
        hsm[par][(wv << 6) + lane] = __uint_as_float((unsigned)w);
      }
      __syncthreads();
      float hv[8];
      if (S > 0) {
        UNROLL for (int k = 0; k < 8; ++k) hv[k] = hsm[par][(k << 6) + lane];
      } else {
        UNROLL for (int k = 0; k < 8; ++k) hv[k] = 0.f;
      }

      float acc[4];
      UNROLL for (int g = 0; g < 4; ++g) {
        float a = 0.f;
        UNROLL for (int k = 0; k < 8; ++k) a += whh[g][k] * hv[k];
        acc[g] = a;
      }
      UNROLL for (int mask = 1; mask < 64; mask <<= 1) {
        UNROLL for (int g = 0; g < 4; ++g) acc[g] += __shfl_xor(acc[g], mask, 64);
      }
      // all lanes hold the recurrent sums; add pre via broadcast shuffle
      float ia = fast_sigmoid(acc[0] + __shfl(pf, 0, 64));
      float fa = fast_sigmoid(acc[1] + __shfl(pf, 1, 64));
      float gg = fast_tanh(acc[2] + __shfl(pf, 2, 64));
      float oa = fast_sigmoid(acc[3] + __shfl(pf, 3, 64));
      c = fa * c + ia * gg;
      float h = oa * fast_tanh(c);

      // stage this wave's tagged word in LDS for the coalesced publish
      if (lane == 0)
        hpub[wv] = ((unsigned long long)(unsigned)(S + 1) << 32) |
                   (unsigned long long)__float_as_uint(h);
      if (phase && lane == 0)
        hsb[((size_t)t << 9) + U] = f2bf_rne(h);  // decoder hs in bf16 for MFMA
      __syncthreads();

      // rotating publisher wave: one 64-lane store covers 8 copies x 8 units,
      // each 8-lane group writing one full contiguous 64B mailbox line
      if (wv == (S & 7)) {
        unsigned long long w = hpub[lane & 7];
        __hip_atomic_store(
            &hword[((lane >> 3) << 10) + (((S + 1) & 1) << 9) + (blk << 3) + (lane & 7)], w,
            __ATOMIC_RELAXED, __HIP_MEMORY_SCOPE_AGENT);
      }
    }
  }
}

// ---------------- logits GEMM (bf16 MFMA) + fused softmax partials ----------------
// grid (250, 4): 128 vocab cols x 128 t rows per block. 256 threads = 4 waves (2x2).
__global__ __launch_bounds__(256, 2) void k_logits(
    const unsigned short* __restrict__ hsb, const float* __restrict__ W_out,
    const float* __restrict__ b_out, const int* __restrict__ target,
    float* __restrict__ pmax, float* __restrict__ psum, float* __restrict__ tgt) {
  const int nt = blockIdx.x;
  const int mt = blockIdx.y;
  const int nbase = nt << 7;
  const int mbase = mt << 7;
  const int tid = threadIdx.x;
  const int l = tid & 63;
  const int q = l >> 4;
  const int cc = l & 15;
  const int W = tid >> 6;
  const int wm = W >> 1, wn = W & 1;

  __shared__ __align__(16) unsigned short Asm[128][40];  // +8 pad: bank spread
  __shared__ __align__(16) unsigned short Bsm[128][40];
  __shared__ float ex[2][128][2];

  f32x4 acc[4][4];
  f32x4 zero = {0.f, 0.f, 0.f, 0.f};
  UNROLL for (int i = 0; i < 4; ++i) UNROLL for (int j = 0; j < 4; ++j) acc[i][j] = zero;

  const int srow = tid >> 1;
  const int sh = tid & 1;

  for (int kc = 0; kc < 16; ++kc) {
    // stage A tile (bf16 hs rows)
    const unsigned short* ap = hsb + (size_t)(mbase + srow) * 512 + (kc << 5) + (sh << 4);
    uint4 a0 = *(const uint4*)ap;
    uint4 a1 = *(const uint4*)(ap + 8);
    *(uint4*)&Asm[srow][(sh << 4)] = a0;
    *(uint4*)&Asm[srow][(sh << 4) + 8] = a1;

    // stage B tile (f32 W_out rows -> bf16)
    const float* bp = W_out + (size_t)(nbase + srow) * 512 + (kc << 5) + (sh << 4);
    float bv[16];
    *(float4*)&bv[0] = *(const float4*)bp;
    *(float4*)&bv[4] = *(const float4*)(bp + 4);
    *(float4*)&bv[8] = *(const float4*)(bp + 8);
    *(float4*)&bv[12] = *(const float4*)(bp + 12);
    unsigned short us[16];
    UNROLL for (int j = 0; j < 16; ++j) us[j] = f2bf_rne(bv[j]);
    *(uint4*)&Bsm[srow][(sh << 4)] = *(const uint4*)&us[0];
    *(uint4*)&Bsm[srow][(sh << 4) + 8] = *(const uint4*)&us[8];

    __syncthreads();

    bf16x8 af[4], bfr[4];
    UNROLL for (int mi = 0; mi < 4; ++mi)
      af[mi] = *(const bf16x8*)((const char*)Asm + (size_t)((wm << 6) + (mi << 4) + cc) * 80 + (q << 4));
    UNROLL for (int ni = 0; ni < 4; ++ni)
      bfr[ni] = *(const bf16x8*)((const char*)Bsm + (size_t)((wn << 6) + (ni << 4) + cc) * 80 + (q << 4));
    UNROLL for (int mi = 0; mi < 4; ++mi)
      UNROLL for (int ni = 0; ni < 4; ++ni)
        acc[mi][ni] = __builtin_amdgcn_mfma_f32_16x16x32_bf16(af[mi], bfr[ni], acc[mi][ni], 0, 0, 0);

    __syncthreads();
  }

  // epilogue: + b_out; per-row (max, sumexp) over this block's 128 cols; target logit
  float bo[4];
  UNROLL for (int ni = 0; ni < 4; ++ni) bo[ni] = b_out[nbase + (wn << 6) + (ni << 4) + cc];
  UNROLL for (int mi = 0; mi < 4; ++mi)
    UNROLL for (int ni = 0; ni < 4; ++ni)
      UNROLL for (int r = 0; r < 4; ++r) acc[mi][ni][r] += bo[ni];

  UNROLL for (int mi = 0; mi < 4; ++mi) {
    UNROLL for (int r = 0; r < 4; ++r) {
      // C/D layout: col = lane&15, row = (lane>>4)*4 + r
      float v0 = acc[mi][0][r], v1 = acc[mi][1][r], v2 = acc[mi][2][r], v3 = acc[mi][3][r];
      float m = fmaxf(fmaxf(v0, v1), fmaxf(v2, v3));
      m = fmaxf(m, __shfl_xor(m, 1));
      m = fmaxf(m, __shfl_xor(m, 2));
      m = fmaxf(m, __shfl_xor(m, 4));
      m = fmaxf(m, __shfl_xor(m, 8));
      float s = __expf(v0 - m) + __expf(v1 - m) + __expf(v2 - m) + __expf(v3 - m);
      s += __shfl_xor(s, 1);
      s += __shfl_xor(s, 2);
      s += __shfl_xor(s, 4);
      s += __shfl_xor(s, 8);
      int rowb = (wm << 6) + (mi << 4) + (q << 2) + r;
      if (cc == 0) { ex[wn][rowb][0] = m; ex[wn][rowb][1] = s; }
      int t = mbase + rowb;
      if (t < 511) {
        int rel = target[t + 1] - nbase - (wn << 6);
        if (rel >= 0 && rel < 64 && (rel & 15) == cc) {
          int nisel = rel >> 4;
          float v = nisel == 0 ? v0 : (nisel == 1 ? v1 : (nisel == 2 ? v2 : v3));
          tgt[t] = v;
        }
      }
    }
  }
  __syncthreads();
  if (tid < 128) {
    int t = mbase + tid;
    if (t < 511) {
      float m0 = ex[0][tid][0], s0 = ex[0][tid][1];
      float m1 = ex[1][tid][0], s1 = ex[1][tid][1];
      float M = fmaxf(m0, m1);
      float S = s0 * __expf(m0 - M) + s1 * __expf(m1 - M);
      pmax[(nt << 9) + t] = M;
      psum[(nt << 9) + t] = S;
    }
  }
}

// ---------------- finalize: combine 250 partials per row ----------------
__global__ void k_loss(const float* __restrict__ pmax, const float* __restrict__ psum,
                       const float* __restrict__ tgt, float* __restrict__ out) {
  int t = threadIdx.x;
  if (t >= 511) return;
  float M = -3.4e38f;
  for (int nt = 0; nt < 250; ++nt) M = fmaxf(M, pmax[(nt << 9) + t]);
  float S = 0.f;
  for (int nt = 0; nt < 250; ++nt) S += psum[(nt << 9) + t] * __expf(pmax[(nt << 9) + t] - M);
  out[t] = M + logf(S) - tgt[t];
}

extern "C" void kernel_launch(void* const* d_in, const int* in_sizes, int n_in,
                              void* d_out, int out_size, void* d_ws, size_t ws_size,
                              hipStream_t stream) {
  const int* source = (const int*)d_in[0];
  const int* target = (const int*)d_in[1];
  const float* enc_embed = (const float*)d_in[2];
  const float* enc_Wih = (const float*)d_in[3];
  const float* enc_Whh = (const float*)d_in[4];
  const float* enc_bih = (const float*)d_in[5];
  const float* enc_bhh = (const float*)d_in[6];
  const float* dec_embed = (const float*)d_in[7];
  const float* dec_Wih = (const float*)d_in[8];
  const float* dec_Whh = (const float*)d_in[9];
  const float* dec_bih = (const float*)d_in[10];
  const float* dec_bhh = (const float*)d_in[11];
  const float* W_out = (const float*)d_in[12];
  const float* b_out = (const float*)d_in[13];
  float* out = (float*)d_out;

  // Workspace map (non-overlapping, ~10.0 MB total):
  char* ws = (char*)d_ws;
  unsigned long long* hword = (unsigned long long*)(ws);  // 8192 u64 = 64 KB
  float* tgt = (float*)(ws + 65536);                      // 512 f32
  unsigned short* hsb = (unsigned short*)(ws + 67584);    // 512*512 bf16 = 512 KB
  float* pmax = (float*)(ws + 591872);                    // 250*512 f32 (stride 512)
  float* psum = (float*)(ws + 1116160);                   // 250*512 f32
  float* pre = (float*)(ws + 1640448);                    // 1023*2048 f32 = 8.38 MB

  k_init<<<1, 256, 0, stream>>>(hword);
  k_pre<<<dim3(16, 8), 256, 0, stream>>>(source, target, enc_embed, enc_Wih, enc_bih, enc_bhh,
                                         dec_embed, dec_Wih, dec_bih, dec_bhh, pre);
  k_lstm<<<64, 512, 0, stream>>>(enc_Whh, dec_Whh, pre, hword, hsb);
  k_logits<<<dim3(250, 4), 256, 0, stream>>>(hsb, W_out, b_out, target, pmax, psum, tgt);
  k_loss<<<1, 512, 0, stream>>>(pmax, psum, tgt, out);
}

// Round 10
// 1832.388 us; speedup vs baseline: 1.0309x; 1.0309x over previous
//
#include <hip/hip_runtime.h>

#define UNROLL _Pragma("unroll")

typedef __attribute__((ext_vector_type(8))) short bf16x8;
typedef __attribute__((ext_vector_type(4))) float f32x4;

__device__ __forceinline__ unsigned short f2bf_rne(float x) {
  unsigned u = __float_as_uint(x);
  unsigned r = (u + 0x7FFFu + ((u >> 16) & 1u)) >> 16;
  return (unsigned short)r;
}

__device__ __forceinline__ float fast_sigmoid(float x) {
  return __builtin_amdgcn_rcpf(1.f + __expf(-x));
}
__device__ __forceinline__ float fast_tanh(float x) {
  return 1.f - 2.f * __builtin_amdgcn_rcpf(__expf(2.f * x) + 1.f);
}

// ---------------- init: reset all 8 mailbox copies (tag=0) ----------------
__global__ void k_init(unsigned long long* hword) {
  int t = threadIdx.x;
  for (int i = t; i < 8192; i += 256) hword[i] = 0ull;  // 8 copies x 2 parities x 512
}

// ---------------- pre-GEMM: pre[step][unit*4+gate] = emb@Wih.T + bih + bhh ----------------
// Teacher forcing: all tokens known -> both LSTMs' input projections are one parallel
// GEMM. grid (16, 8): nt over 2048 gate-rows, mt over 1024 step-rows (mt<4 = encoder
// rows 0..511 from source; mt>=4 = decoder rows 512..1022 from target[0..510]).
__global__ __launch_bounds__(256, 2) void k_pre(
    const int* __restrict__ source, const int* __restrict__ target,
    const float* __restrict__ enc_embed, const float* __restrict__ enc_Wih,
    const float* __restrict__ enc_bih, const float* __restrict__ enc_bhh,
    const float* __restrict__ dec_embed, const float* __restrict__ dec_Wih,
    const float* __restrict__ dec_bih, const float* __restrict__ dec_bhh,
    float* __restrict__ pre) {
  const int nt = blockIdx.x;
  const int mt = blockIdx.y;
  const int phase = mt >> 2;
  const int nbase = nt << 7;
  const int mbase = mt << 7;
  const int tid = threadIdx.x;
  const int l = tid & 63;
  const int q = l >> 4;
  const int cc = l & 15;
  const int W = tid >> 6;
  const int wm = W >> 1, wn = W & 1;

  const float* emb = phase ? dec_embed : enc_embed;
  const float* Wih = phase ? dec_Wih : enc_Wih;
  const float* bih = phase ? dec_bih : enc_bih;
  const float* bhh = phase ? dec_bhh : enc_bhh;

  __shared__ __align__(16) unsigned short Asm[128][40];
  __shared__ __align__(16) unsigned short Bsm[128][40];

  f32x4 acc[4][4];
  f32x4 zero = {0.f, 0.f, 0.f, 0.f};
  UNROLL for (int i = 0; i < 4; ++i) UNROLL for (int j = 0; j < 4; ++j) acc[i][j] = zero;

  const int srow = tid >> 1;
  const int sh = tid & 1;
  const int m = mbase + srow;
  int tok;
  if (phase == 0) {
    tok = source[m];
  } else {
    int rel = m - 512;
    tok = (rel < 511) ? target[rel] : 0;  // row 1023 is a dummy (stores guarded)
  }
  const float* arow = emb + (size_t)tok * 512;
  const float* brow = Wih + (size_t)(nbase + srow) * 512;

  for (int kc = 0; kc < 16; ++kc) {
    // stage A tile (gathered embedding rows, f32 -> bf16)
    {
      const float* ap = arow + (kc << 5) + (sh << 4);
      float av[16];
      *(float4*)&av[0] = *(const float4*)ap;
      *(float4*)&av[4] = *(const float4*)(ap + 4);
      *(float4*)&av[8] = *(const float4*)(ap + 8);
      *(float4*)&av[12] = *(const float4*)(ap + 12);
      unsigned short us[16];
      UNROLL for (int j = 0; j < 16; ++j) us[j] = f2bf_rne(av[j]);
      *(uint4*)&Asm[srow][(sh << 4)] = *(const uint4*)&us[0];
      *(uint4*)&Asm[srow][(sh << 4) + 8] = *(const uint4*)&us[8];
    }
    // stage B tile (Wih rows, f32 -> bf16)
    {
      const float* bp = brow + (kc << 5) + (sh << 4);
      float bv[16];
      *(float4*)&bv[0] = *(const float4*)bp;
      *(float4*)&bv[4] = *(const float4*)(bp + 4);
      *(float4*)&bv[8] = *(const float4*)(bp + 8);
      *(float4*)&bv[12] = *(const float4*)(bp + 12);
      unsigned short us[16];
      UNROLL for (int j = 0; j < 16; ++j) us[j] = f2bf_rne(bv[j]);
      *(uint4*)&Bsm[srow][(sh << 4)] = *(const uint4*)&us[0];
      *(uint4*)&Bsm[srow][(sh << 4) + 8] = *(const uint4*)&us[8];
    }
    __syncthreads();

    bf16x8 af[4], bfr[4];
    UNROLL for (int mi = 0; mi < 4; ++mi)
      af[mi] = *(const bf16x8*)((const char*)Asm + (size_t)((wm << 6) + (mi << 4) + cc) * 80 + (q << 4));
    UNROLL for (int ni = 0; ni < 4; ++ni)
      bfr[ni] = *(const bf16x8*)((const char*)Bsm + (size_t)((wn << 6) + (ni << 4) + cc) * 80 + (q << 4));
    UNROLL for (int mi = 0; mi < 4; ++mi)
      UNROLL for (int ni = 0; ni < 4; ++ni)
        acc[mi][ni] = __builtin_amdgcn_mfma_f32_16x16x32_bf16(af[mi], bfr[ni], acc[mi][ni], 0, 0, 0);

    __syncthreads();
  }

  // epilogue: + (bih+bhh); scatter to pre[m][ (u&511)*4 + gate ]
  float bo[4];
  UNROLL for (int ni = 0; ni < 4; ++ni) {
    int cr = nbase + (wn << 6) + (ni << 4) + cc;
    bo[ni] = bih[cr] + bhh[cr];
  }
  UNROLL for (int mi = 0; mi < 4; ++mi) {
    UNROLL for (int r = 0; r < 4; ++r) {
      int rowb = (wm << 6) + (mi << 4) + (q << 2) + r;  // C/D: col=lane&15, row=(lane>>4)*4+r
      int m2 = mbase + rowb;
      if (phase == 0 || m2 < 1023) {
        UNROLL for (int ni = 0; ni < 4; ++ni) {
          int cr = nbase + (wn << 6) + (ni << 4) + cc;
          pre[(size_t)m2 * 2048 + ((cr & 511) << 2) + (cr >> 9)] = acc[mi][ni][r] + bo[ni];
        }
      }
    }
  }
}

// ---------------- persistent sequential LSTM (enc 512 + dec 511 steps) ----------------
// Round-8 structure (immediate lane<8 exchange publish — best measured). ONLY delta:
// SOFTWARE-PIPELINED POLL with 4 outstanding samples (w0..w3, named regs). Each
// check waits only on its own sample (oldest, vmcnt(3)) and is followed by one
// reissue, so samples self-space at ~RTT/4: observation quantization (and its
// 512-wave tail-max) drops ~4x vs the serial load->check loop.
// 64 blocks x 512 threads (8 waves). Wave wv of block b computes unit U = 8b+wv.
// Publish: lanes 0..7 exchange tagged u64 {tag=step, f32 h} into all 8 replicated
// mailbox copies in ONE instruction. Block b polls only copy b&7. Tags ride in the
// words; parity double-buffer; k_init re-zeroes -> replay safe.
__global__ __launch_bounds__(512, 1) void k_lstm(
    const float* __restrict__ enc_Whh, const float* __restrict__ dec_Whh,
    const float* __restrict__ pre, unsigned long long* hword, unsigned short* hsb) {
  const int blk = blockIdx.x;
  const int tid = threadIdx.x;
  const int lane = tid & 63;
  const int wv = tid >> 6;
  const int U = (blk << 3) + wv;  // global hidden unit
  const int mycopy = blk & 7;

  __shared__ float hsm[2][512];  // parity-split broadcast buffer (1 barrier/step)

  float c = 0.f;

  for (int phase = 0; phase < 2; ++phase) {
    const float* Whh = phase ? dec_Whh : enc_Whh;

    float whh[4][8];
    UNROLL for (int g = 0; g < 4; ++g) {
      const float* p2 = Whh + (size_t)((g << 9) + U) * 512 + lane;
      UNROLL for (int k = 0; k < 8; ++k) whh[g][k] = p2[k << 6];
    }
    UNROLL for (int g = 0; g < 4; ++g) UNROLL for (int k = 0; k < 8; ++k)
      asm volatile("" : "+v"(whh[g][k]));

    const int T = phase ? 511 : 512;
    for (int t = 0; t < T; ++t) {
      const int S = (phase ? 512 : 0) + t;  // consume state-after-S-steps
      const int par = S & 1;

      // this wave's 4 gate pre-activations (pre = emb@Wih.T + biases), issued
      // before the poll so MALL latency hides under the spin
      float pf = pre[(size_t)S * 2048 + (U << 2) + (lane & 3)];
      asm volatile("" : "+v"(pf));  // don't sink past the poll

      // pipelined poll: 4 outstanding samples of this wave's 64-unit slice
      if (S > 0) {
        const unsigned long long* hw = hword + (mycopy << 10) + (par << 9) + (wv << 6) + lane;
        const unsigned tg = (unsigned)S;
#define PLOAD() __hip_atomic_load(hw, __ATOMIC_RELAXED, __HIP_MEMORY_SCOPE_AGENT)
        unsigned long long w0 = PLOAD();
        unsigned long long w1 = PLOAD();
        unsigned long long w2 = PLOAD();
        unsigned long long w3 = PLOAD();
        unsigned long long w;
        while (true) {
          if (__all((unsigned)(w0 >> 32) == tg)) { w = w0; break; }
          w0 = PLOAD();
          if (__all((unsigned)(w1 >> 32) == tg)) { w = w1; break; }
          w1 = PLOAD();
          if (__all((unsigned)(w2 >> 32) == tg)) { w = w2; break; }
          w2 = PLOAD();
          if (__all((unsigned)(w3 >> 32) == tg)) { w = w3; break; }
          w3 = PLOAD();
        }
#undef PLOAD
        hsm[par][(wv << 6) + lane] = __uint_as_float((unsigned)w);
      }
      __syncthreads();
      float hv[8];
      if (S > 0) {
        UNROLL for (int k = 0; k < 8; ++k) hv[k] = hsm[par][(k << 6) + lane];
      } else {
        UNROLL for (int k = 0; k < 8; ++k) hv[k] = 0.f;
      }

      float acc[4];
      UNROLL for (int g = 0; g < 4; ++g) {
        float a = 0.f;
        UNROLL for (int k = 0; k < 8; ++k) a += whh[g][k] * hv[k];
        acc[g] = a;
      }
      UNROLL for (int mask = 1; mask < 64; mask <<= 1) {
        UNROLL for (int g = 0; g < 4; ++g) acc[g] += __shfl_xor(acc[g], mask, 64);
      }
      // all lanes hold the recurrent sums; add pre via broadcast shuffle
      float ia = fast_sigmoid(acc[0] + __shfl(pf, 0, 64));
      float fa = fast_sigmoid(acc[1] + __shfl(pf, 1, 64));
      float gg = fast_tanh(acc[2] + __shfl(pf, 2, 64));
      float oa = fast_sigmoid(acc[3] + __shfl(pf, 3, 64));
      c = fa * c + ia * gg;
      float h = oa * fast_tanh(c);

      if (lane < 8) {
        unsigned long long w =
            ((unsigned long long)(unsigned)(S + 1) << 32) | (unsigned long long)__float_as_uint(h);
        // RMW executes at the coherence point; issued immediately after h is ready
        (void)__hip_atomic_exchange(&hword[(lane << 10) + (((S + 1) & 1) << 9) + U], w,
                                    __ATOMIC_RELAXED, __HIP_MEMORY_SCOPE_AGENT);
      }
      if (phase && lane == 0)
        hsb[((size_t)t << 9) + U] = f2bf_rne(h);  // decoder hs in bf16 for MFMA
    }
  }
}

// ---------------- logits GEMM (bf16 MFMA) + fused softmax partials ----------------
// grid (250, 4): 128 vocab cols x 128 t rows per block. 256 threads = 4 waves (2x2).
__global__ __launch_bounds__(256, 2) void k_logits(
    const unsigned short* __restrict__ hsb, const float* __restrict__ W_out,
    const float* __restrict__ b_out, const int* __restrict__ target,
    float* __restrict__ pmax, float* __restrict__ psum, float* __restrict__ tgt) {
  const int nt = blockIdx.x;
  const int mt = blockIdx.y;
  const int nbase = nt << 7;
  const int mbase = mt << 7;
  const int tid = threadIdx.x;
  const int l = tid & 63;
  const int q = l >> 4;
  const int cc = l & 15;
  const int W = tid >> 6;
  const int wm = W >> 1, wn = W & 1;

  __shared__ __align__(16) unsigned short Asm[128][40];  // +8 pad: bank spread
  __shared__ __align__(16) unsigned short Bsm[128][40];
  __shared__ float ex[2][128][2];

  f32x4 acc[4][4];
  f32x4 zero = {0.f, 0.f, 0.f, 0.f};
  UNROLL for (int i = 0; i < 4; ++i) UNROLL for (int j = 0; j < 4; ++j) acc[i][j] = zero;

  const int srow = tid >> 1;
  const int sh = tid & 1;

  for (int kc = 0; kc < 16; ++kc) {
    // stage A tile (bf16 hs rows)
    const unsigned short* ap = hsb + (size_t)(mbase + srow) * 512 + (kc << 5) + (sh << 4);
    uint4 a0 = *(const uint4*)ap;
    uint4 a1 = *(const uint4*)(ap + 8);
    *(uint4*)&Asm[srow][(sh << 4)] = a0;
    *(uint4*)&Asm[srow][(sh << 4) + 8] = a1;

    // stage B tile (f32 W_out rows -> bf16)
    const float* bp = W_out + (size_t)(nbase + srow) * 512 + (kc << 5) + (sh << 4);
    float bv[16];
    *(float4*)&bv[0] = *(const float4*)bp;
    *(float4*)&bv[4] = *(const float4*)(bp + 4);
    *(float4*)&bv[8] = *(const float4*)(bp + 8);
    *(float4*)&bv[12] = *(const float4*)(bp + 12);
    unsigned short us[16];
    UNROLL for (int j = 0; j < 16; ++j) us[j] = f2bf_rne(bv[j]);
    *(uint4*)&Bsm[srow][(sh << 4)] = *(const uint4*)&us[0];
    *(uint4*)&Bsm[srow][(sh << 4) + 8] = *(const uint4*)&us[8];

    __syncthreads();

    bf16x8 af[4], bfr[4];
    UNROLL for (int mi = 0; mi < 4; ++mi)
      af[mi] = *(const bf16x8*)((const char*)Asm + (size_t)((wm << 6) + (mi << 4) + cc) * 80 + (q << 4));
    UNROLL for (int ni = 0; ni < 4; ++ni)
      bfr[ni] = *(const bf16x8*)((const char*)Bsm + (size_t)((wn << 6) + (ni << 4) + cc) * 80 + (q << 4));
    UNROLL for (int mi = 0; mi < 4; ++mi)
      UNROLL for (int ni = 0; ni < 4; ++ni)
        acc[mi][ni] = __builtin_amdgcn_mfma_f32_16x16x32_bf16(af[mi], bfr[ni], acc[mi][ni], 0, 0, 0);

    __syncthreads();
  }

  // epilogue: + b_out; per-row (max, sumexp) over this block's 128 cols; target logit
  float bo[4];
  UNROLL for (int ni = 0; ni < 4; ++ni) bo[ni] = b_out[nbase + (wn << 6) + (ni << 4) + cc];
  UNROLL for (int mi = 0; mi < 4; ++mi)
    UNROLL for (int ni = 0; ni < 4; ++ni)
      UNROLL for (int r = 0; r < 4; ++r) acc[mi][ni][r] += bo[ni];

  UNROLL for (int mi = 0; mi < 4; ++mi) {
    UNROLL for (int r = 0; r < 4; ++r) {
      // C/D layout: col = lane&15, row = (lane>>4)*4 + r
      float v0 = acc[mi][0][r], v1 = acc[mi][1][r], v2 = acc[mi][2][r], v3 = acc[mi][3][r];
      float m = fmaxf(fmaxf(v0, v1), fmaxf(v2, v3));
      m = fmaxf(m, __shfl_xor(m, 1));
      m = fmaxf(m, __shfl_xor(m, 2));
      m = fmaxf(m, __shfl_xor(m, 4));
      m = fmaxf(m, __shfl_xor(m, 8));
      float s = __expf(v0 - m) + __expf(v1 - m) + __expf(v2 - m) + __expf(v3 - m);
      s += __shfl_xor(s, 1);
      s += __shfl_xor(s, 2);
      s += __shfl_xor(s, 4);
      s += __shfl_xor(s, 8);
      int rowb = (wm << 6) + (mi << 4) + (q << 2) + r;
      if (cc == 0) { ex[wn][rowb][0] = m; ex[wn][rowb][1] = s; }
      int t = mbase + rowb;
      if (t < 511) {
        int rel = target[t + 1] - nbase - (wn << 6);
        if (rel >= 0 && rel < 64 && (rel & 15) == cc) {
          int nisel = rel >> 4;
          float v = nisel == 0 ? v0 : (nisel == 1 ? v1 : (nisel == 2 ? v2 : v3));
          tgt[t] = v;
        }
      }
    }
  }
  __syncthreads();
  if (tid < 128) {
    int t = mbase + tid;
    if (t < 511) {
      float m0 = ex[0][tid][0], s0 = ex[0][tid][1];
      float m1 = ex[1][tid][0], s1 = ex[1][tid][1];
      float M = fmaxf(m0, m1);
      float S = s0 * __expf(m0 - M) + s1 * __expf(m1 - M);
      pmax[(nt << 9) + t] = M;
      psum[(nt << 9) + t] = S;
    }
  }
}

// ---------------- finalize: combine 250 partials per row ----------------
__global__ void k_loss(const float* __restrict__ pmax, const float* __restrict__ psum,
                       const float* __restrict__ tgt, float* __restrict__ out) {
  int t = threadIdx.x;
  if (t >= 511) return;
  float M = -3.4e38f;
  for (int nt = 0; nt < 250; ++nt) M = fmaxf(M, pmax[(nt << 9) + t]);
  float S = 0.f;
  for (int nt = 0; nt < 250; ++nt) S += psum[(nt << 9) + t] * __expf(pmax[(nt << 9) + t] - M);
  out[t] = M + logf(S) - tgt[t];
}

extern "C" void kernel_launch(void* const* d_in, const int* in_sizes, int n_in,
                              void* d_out, int out_size, void* d_ws, size_t ws_size,
                              hipStream_t stream) {
  const int* source = (const int*)d_in[0];
  const int* target = (const int*)d_in[1];
  const float* enc_embed = (const float*)d_in[2];
  const float* enc_Wih = (const float*)d_in[3];
  const float* enc_Whh = (const float*)d_in[4];
  const float* enc_bih = (const float*)d_in[5];
  const float* enc_bhh = (const float*)d_in[6];
  const float* dec_embed = (const float*)d_in[7];
  const float* dec_Wih = (const float*)d_in[8];
  const float* dec_Whh = (const float*)d_in[9];
  const float* dec_bih = (const float*)d_in[10];
  const float* dec_bhh = (const float*)d_in[11];
  const float* W_out = (const float*)d_in[12];
  const float* b_out = (const float*)d_in[13];
  float* out = (float*)d_out;

  // Workspace map (non-overlapping, ~10.0 MB total):
  char* ws = (char*)d_ws;
  unsigned long long* hword = (unsigned long long*)(ws);  // 8192 u64 = 64 KB
  float* tgt = (float*)(ws + 65536);                      // 512 f32
  unsigned short* hsb = (unsigned short*)(ws + 67584);    // 512*512 bf16 = 512 KB
  float* pmax = (float*)(ws + 591872);                    // 250*512 f32 (stride 512)
  float* psum = (float*)(ws + 1116160);                   // 250*512 f32
  float* pre = (float*)(ws + 1640448);                    // 1023*2048 f32 = 8.38 MB

  k_init<<<1, 256, 0, stream>>>(hword);
  k_pre<<<dim3(16, 8), 256, 0, stream>>>(source, target, enc_embed, enc_Wih, enc_bih, enc_bhh,
                                         dec_embed, dec_Wih, dec_bih, dec_bhh, pre);
  k_lstm<<<64, 512, 0, stream>>>(enc_Whh, dec_Whh, pre, hword, hsb);
  k_logits<<<dim3(250, 4), 256, 0, stream>>>(hsb, W_out, b_out, target, pmax, psum, tgt);
  k_loss<<<1, 512, 0, stream>>>(pmax, psum, tgt, out);
}

// Round 11
// 1635.849 us; speedup vs baseline: 1.1547x; 1.1201x over previous
//
#include <hip/hip_runtime.h>

#define UNROLL _Pragma("unroll")

typedef __attribute__((ext_vector_type(8))) short bf16x8;
typedef __attribute__((ext_vector_type(4))) float f32x4;

__device__ __forceinline__ unsigned short f2bf_rne(float x) {
  unsigned u = __float_as_uint(x);
  unsigned r = (u + 0x7FFFu + ((u >> 16) & 1u)) >> 16;
  return (unsigned short)r;
}

__device__ __forceinline__ float fast_sigmoid(float x) {
  return __builtin_amdgcn_rcpf(1.f + __expf(-x));
}
__device__ __forceinline__ float fast_tanh(float x) {
  return 1.f - 2.f * __builtin_amdgcn_rcpf(__expf(2.f * x) + 1.f);
}

// ---------------- pre-GEMM: pre[step][unit*4+gate] = emb@Wih.T + bih + bhh ----------------
// Teacher forcing: all tokens known -> both LSTMs' input projections are one parallel
// GEMM. grid (16, 8): nt over 2048 gate-rows, mt over 1024 step-rows (mt<4 = encoder
// rows 0..511 from source; mt>=4 = decoder rows 512..1022 from target[0..510]).
// Also fused: nt==0 blocks zero the hword mailboxes (replaces the old k_init launch;
// kernel-boundary ordering guarantees completion before k_lstm starts).
__global__ __launch_bounds__(256, 2) void k_pre(
    const int* __restrict__ source, const int* __restrict__ target,
    const float* __restrict__ enc_embed, const float* __restrict__ enc_Wih,
    const float* __restrict__ enc_bih, const float* __restrict__ enc_bhh,
    const float* __restrict__ dec_embed, const float* __restrict__ dec_Wih,
    const float* __restrict__ dec_bih, const float* __restrict__ dec_bhh,
    float* __restrict__ pre, unsigned long long* __restrict__ hword) {
  const int nt = blockIdx.x;
  const int mt = blockIdx.y;
  const int phase = mt >> 2;
  const int nbase = nt << 7;
  const int mbase = mt << 7;
  const int tid = threadIdx.x;
  const int l = tid & 63;
  const int q = l >> 4;
  const int cc = l & 15;
  const int W = tid >> 6;
  const int wm = W >> 1, wn = W & 1;

  // fused mailbox init: 8 blocks (nt==0, mt 0..7) cover 8192 words
  if (nt == 0) {
    UNROLL for (int i = 0; i < 4; ++i) hword[(mt << 10) + (i << 8) + tid] = 0ull;
  }

  const float* emb = phase ? dec_embed : enc_embed;
  const float* Wih = phase ? dec_Wih : enc_Wih;
  const float* bih = phase ? dec_bih : enc_bih;
  const float* bhh = phase ? dec_bhh : enc_bhh;

  __shared__ __align__(16) unsigned short Asm[128][40];
  __shared__ __align__(16) unsigned short Bsm[128][40];

  f32x4 acc[4][4];
  f32x4 zero = {0.f, 0.f, 0.f, 0.f};
  UNROLL for (int i = 0; i < 4; ++i) UNROLL for (int j = 0; j < 4; ++j) acc[i][j] = zero;

  const int srow = tid >> 1;
  const int sh = tid & 1;
  const int m = mbase + srow;
  int tok;
  if (phase == 0) {
    tok = source[m];
  } else {
    int rel = m - 512;
    tok = (rel < 511) ? target[rel] : 0;  // row 1023 is a dummy (stores guarded)
  }
  const float* arow = emb + (size_t)tok * 512;
  const float* brow = Wih + (size_t)(nbase + srow) * 512;

  for (int kc = 0; kc < 16; ++kc) {
    // stage A tile (gathered embedding rows, f32 -> bf16)
    {
      const float* ap = arow + (kc << 5) + (sh << 4);
      float av[16];
      *(float4*)&av[0] = *(const float4*)ap;
      *(float4*)&av[4] = *(const float4*)(ap + 4);
      *(float4*)&av[8] = *(const float4*)(ap + 8);
      *(float4*)&av[12] = *(const float4*)(ap + 12);
      unsigned short us[16];
      UNROLL for (int j = 0; j < 16; ++j) us[j] = f2bf_rne(av[j]);
      *(uint4*)&Asm[srow][(sh << 4)] = *(const uint4*)&us[0];
      *(uint4*)&Asm[srow][(sh << 4) + 8] = *(const uint4*)&us[8];
    }
    // stage B tile (Wih rows, f32 -> bf16)
    {
      const float* bp = brow + (kc << 5) + (sh << 4);
      float bv[16];
      *(float4*)&bv[0] = *(const float4*)bp;
      *(float4*)&bv[4] = *(const float4*)(bp + 4);
      *(float4*)&bv[8] = *(const float4*)(bp + 8);
      *(float4*)&bv[12] = *(const float4*)(bp + 12);
      unsigned short us[16];
      UNROLL for (int j = 0; j < 16; ++j) us[j] = f2bf_rne(bv[j]);
      *(uint4*)&Bsm[srow][(sh << 4)] = *(const uint4*)&us[0];
      *(uint4*)&Bsm[srow][(sh << 4) + 8] = *(const uint4*)&us[8];
    }
    __syncthreads();

    bf16x8 af[4], bfr[4];
    UNROLL for (int mi = 0; mi < 4; ++mi)
      af[mi] = *(const bf16x8*)((const char*)Asm + (size_t)((wm << 6) + (mi << 4) + cc) * 80 + (q << 4));
    UNROLL for (int ni = 0; ni < 4; ++ni)
      bfr[ni] = *(const bf16x8*)((const char*)Bsm + (size_t)((wn << 6) + (ni << 4) + cc) * 80 + (q << 4));
    UNROLL for (int mi = 0; mi < 4; ++mi)
      UNROLL for (int ni = 0; ni < 4; ++ni)
        acc[mi][ni] = __builtin_amdgcn_mfma_f32_16x16x32_bf16(af[mi], bfr[ni], acc[mi][ni], 0, 0, 0);

    __syncthreads();
  }

  // epilogue: + (bih+bhh); scatter to pre[m][ (u&511)*4 + gate ]
  float bo[4];
  UNROLL for (int ni = 0; ni < 4; ++ni) {
    int cr = nbase + (wn << 6) + (ni << 4) + cc;
    bo[ni] = bih[cr] + bhh[cr];
  }
  UNROLL for (int mi = 0; mi < 4; ++mi) {
    UNROLL for (int r = 0; r < 4; ++r) {
      int rowb = (wm << 6) + (mi << 4) + (q << 2) + r;  // C/D: col=lane&15, row=(lane>>4)*4+r
      int m2 = mbase + rowb;
      if (phase == 0 || m2 < 1023) {
        UNROLL for (int ni = 0; ni < 4; ++ni) {
          int cr = nbase + (wn << 6) + (ni << 4) + cc;
          pre[(size_t)m2 * 2048 + ((cr & 511) << 2) + (cr >> 9)] = acc[mi][ni][r] + bo[ni];
        }
      }
    }
  }
}

// ---------------- persistent sequential LSTM (enc 512 + dec 511 steps) ----------------
// ROUND-8 configuration, byte-for-byte (best measured: ~1.52us/step). Immediate
// lane<8 exchange publish + one-outstanding serial poll + 8 replicated mailboxes.
// Round 9 (coalesced LDS publish) and round 10 (4-deep pipelined poll) both
// regressed — this is the measured sync floor for this topology.
// 64 blocks x 512 threads (8 waves). Wave wv of block b computes unit U = 8b+wv.
// Publish: lanes 0..7 exchange tagged u64 {tag=step, f32 h} into all 8 replicated
// mailbox copies in ONE instruction. Block b polls only copy b&7. Tags ride in the
// words; parity double-buffer; k_pre re-zeroes mailboxes -> replay safe.
__global__ __launch_bounds__(512, 1) void k_lstm(
    const float* __restrict__ enc_Whh, const float* __restrict__ dec_Whh,
    const float* __restrict__ pre, unsigned long long* hword, unsigned short* hsb) {
  const int blk = blockIdx.x;
  const int tid = threadIdx.x;
  const int lane = tid & 63;
  const int wv = tid >> 6;
  const int U = (blk << 3) + wv;  // global hidden unit
  const int mycopy = blk & 7;

  __shared__ float hsm[2][512];  // parity-split broadcast buffer (1 barrier/step)

  float c = 0.f;

  for (int phase = 0; phase < 2; ++phase) {
    const float* Whh = phase ? dec_Whh : enc_Whh;

    float whh[4][8];
    UNROLL for (int g = 0; g < 4; ++g) {
      const float* p2 = Whh + (size_t)((g << 9) + U) * 512 + lane;
      UNROLL for (int k = 0; k < 8; ++k) whh[g][k] = p2[k << 6];
    }
    UNROLL for (int g = 0; g < 4; ++g) UNROLL for (int k = 0; k < 8; ++k)
      asm volatile("" : "+v"(whh[g][k]));

    const int T = phase ? 511 : 512;
    for (int t = 0; t < T; ++t) {
      const int S = (phase ? 512 : 0) + t;  // consume state-after-S-steps
      const int par = S & 1;

      // this wave's 4 gate pre-activations (pre = emb@Wih.T + biases), issued
      // before the poll so MALL latency hides under the spin
      float pf = pre[(size_t)S * 2048 + (U << 2) + (lane & 3)];
      asm volatile("" : "+v"(pf));  // don't sink past the poll

      // wave wv polls its 64-unit slice of THIS block's mailbox copy
      if (S > 0) {
        const unsigned long long* hw = hword + (mycopy << 10) + (par << 9) + (wv << 6) + lane;
        unsigned long long w;
        do {
          w = __hip_atomic_load(hw, __ATOMIC_RELAXED, __HIP_MEMORY_SCOPE_AGENT);
        } while (!__all((unsigned)(w >> 32) == (unsigned)S));
        hsm[par][(wv << 6) + lane] = __uint_as_float((unsigned)w);
      }
      __syncthreads();
      float hv[8];
      if (S > 0) {
        UNROLL for (int k = 0; k < 8; ++k) hv[k] = hsm[par][(k << 6) + lane];
      } else {
        UNROLL for (int k = 0; k < 8; ++k) hv[k] = 0.f;
      }

      float acc[4];
      UNROLL for (int g = 0; g < 4; ++g) {
        float a = 0.f;
        UNROLL for (int k = 0; k < 8; ++k) a += whh[g][k] * hv[k];
        acc[g] = a;
      }
      UNROLL for (int mask = 1; mask < 64; mask <<= 1) {
        UNROLL for (int g = 0; g < 4; ++g) acc[g] += __shfl_xor(acc[g], mask, 64);
      }
      // all lanes hold the recurrent sums; add pre via broadcast shuffle
      float ia = fast_sigmoid(acc[0] + __shfl(pf, 0, 64));
      float fa = fast_sigmoid(acc[1] + __shfl(pf, 1, 64));
      float gg = fast_tanh(acc[2] + __shfl(pf, 2, 64));
      float oa = fast_sigmoid(acc[3] + __shfl(pf, 3, 64));
      c = fa * c + ia * gg;
      float h = oa * fast_tanh(c);

      if (lane < 8) {
        unsigned long long w =
            ((unsigned long long)(unsigned)(S + 1) << 32) | (unsigned long long)__float_as_uint(h);
        // RMW executes at the coherence point; issued immediately after h is ready
        (void)__hip_atomic_exchange(&hword[(lane << 10) + (((S + 1) & 1) << 9) + U], w,
                                    __ATOMIC_RELAXED, __HIP_MEMORY_SCOPE_AGENT);
      }
      if (phase && lane == 0)
        hsb[((size_t)t << 9) + U] = f2bf_rne(h);  // decoder hs in bf16 for MFMA
    }
  }
}

// ---------------- logits GEMM (bf16 MFMA) + fused softmax partials ----------------
// grid (250, 4): 128 vocab cols x 128 t rows per block. 256 threads = 4 waves (2x2).
__global__ __launch_bounds__(256, 2) void k_logits(
    const unsigned short* __restrict__ hsb, const float* __restrict__ W_out,
    const float* __restrict__ b_out, const int* __restrict__ target,
    float* __restrict__ pmax, float* __restrict__ psum, float* __restrict__ tgt) {
  const int nt = blockIdx.x;
  const int mt = blockIdx.y;
  const int nbase = nt << 7;
  const int mbase = mt << 7;
  const int tid = threadIdx.x;
  const int l = tid & 63;
  const int q = l >> 4;
  const int cc = l & 15;
  const int W = tid >> 6;
  const int wm = W >> 1, wn = W & 1;

  __shared__ __align__(16) unsigned short Asm[128][40];  // +8 pad: bank spread
  __shared__ __align__(16) unsigned short Bsm[128][40];
  __shared__ float ex[2][128][2];

  f32x4 acc[4][4];
  f32x4 zero = {0.f, 0.f, 0.f, 0.f};
  UNROLL for (int i = 0; i < 4; ++i) UNROLL for (int j = 0; j < 4; ++j) acc[i][j] = zero;

  const int srow = tid >> 1;
  const int sh = tid & 1;

  for (int kc = 0; kc < 16; ++kc) {
    // stage A tile (bf16 hs rows)
    const unsigned short* ap = hsb + (size_t)(mbase + srow) * 512 + (kc << 5) + (sh << 4);
    uint4 a0 = *(const uint4*)ap;
    uint4 a1 = *(const uint4*)(ap + 8);
    *(uint4*)&Asm[srow][(sh << 4)] = a0;
    *(uint4*)&Asm[srow][(sh << 4) + 8] = a1;

    // stage B tile (f32 W_out rows -> bf16)
    const float* bp = W_out + (size_t)(nbase + srow) * 512 + (kc << 5) + (sh << 4);
    float bv[16];
    *(float4*)&bv[0] = *(const float4*)bp;
    *(float4*)&bv[4] = *(const float4*)(bp + 4);
    *(float4*)&bv[8] = *(const float4*)(bp + 8);
    *(float4*)&bv[12] = *(const float4*)(bp + 12);
    unsigned short us[16];
    UNROLL for (int j = 0; j < 16; ++j) us[j] = f2bf_rne(bv[j]);
    *(uint4*)&Bsm[srow][(sh << 4)] = *(const uint4*)&us[0];
    *(uint4*)&Bsm[srow][(sh << 4) + 8] = *(const uint4*)&us[8];

    __syncthreads();

    bf16x8 af[4], bfr[4];
    UNROLL for (int mi = 0; mi < 4; ++mi)
      af[mi] = *(const bf16x8*)((const char*)Asm + (size_t)((wm << 6) + (mi << 4) + cc) * 80 + (q << 4));
    UNROLL for (int ni = 0; ni < 4; ++ni)
      bfr[ni] = *(const bf16x8*)((const char*)Bsm + (size_t)((wn << 6) + (ni << 4) + cc) * 80 + (q << 4));
    UNROLL for (int mi = 0; mi < 4; ++mi)
      UNROLL for (int ni = 0; ni < 4; ++ni)
        acc[mi][ni] = __builtin_amdgcn_mfma_f32_16x16x32_bf16(af[mi], bfr[ni], acc[mi][ni], 0, 0, 0);

    __syncthreads();
  }

  // epilogue: + b_out; per-row (max, sumexp) over this block's 128 cols; target logit
  float bo[4];
  UNROLL for (int ni = 0; ni < 4; ++ni) bo[ni] = b_out[nbase + (wn << 6) + (ni << 4) + cc];
  UNROLL for (int mi = 0; mi < 4; ++mi)
    UNROLL for (int ni = 0; ni < 4; ++ni)
      UNROLL for (int r = 0; r < 4; ++r) acc[mi][ni][r] += bo[ni];

  UNROLL for (int mi = 0; mi < 4; ++mi) {
    UNROLL for (int r = 0; r < 4; ++r) {
      // C/D layout: col = lane&15, row = (lane>>4)*4 + r
      float v0 = acc[mi][0][r], v1 = acc[mi][1][r], v2 = acc[mi][2][r], v3 = acc[mi][3][r];
      float m = fmaxf(fmaxf(v0, v1), fmaxf(v2, v3));
      m = fmaxf(m, __shfl_xor(m, 1));
      m = fmaxf(m, __shfl_xor(m, 2));
      m = fmaxf(m, __shfl_xor(m, 4));
      m = fmaxf(m, __shfl_xor(m, 8));
      float s = __expf(v0 - m) + __expf(v1 - m) + __expf(v2 - m) + __expf(v3 - m);
      s += __shfl_xor(s, 1);
      s += __shfl_xor(s, 2);
      s += __shfl_xor(s, 4);
      s += __shfl_xor(s, 8);
      int rowb = (wm << 6) + (mi << 4) + (q << 2) + r;
      if (cc == 0) { ex[wn][rowb][0] = m; ex[wn][rowb][1] = s; }
      int t = mbase + rowb;
      if (t < 511) {
        int rel = target[t + 1] - nbase - (wn << 6);
        if (rel >= 0 && rel < 64 && (rel & 15) == cc) {
          int nisel = rel >> 4;
          float v = nisel == 0 ? v0 : (nisel == 1 ? v1 : (nisel == 2 ? v2 : v3));
          tgt[t] = v;
        }
      }
    }
  }
  __syncthreads();
  if (tid < 128) {
    int t = mbase + tid;
    if (t < 511) {
      float m0 = ex[0][tid][0], s0 = ex[0][tid][1];
      float m1 = ex[1][tid][0], s1 = ex[1][tid][1];
      float M = fmaxf(m0, m1);
      float S = s0 * __expf(m0 - M) + s1 * __expf(m1 - M);
      pmax[(nt << 9) + t] = M;
      psum[(nt << 9) + t] = S;
    }
  }
}

// ---------------- finalize: combine 250 partials per row (parallel) ----------------
// grid (511) blocks x 256 threads: thread i holds partial nt=i (i<250); two-phase
// block reduction (max, then sum of psum*exp(pmax-M)).
__global__ void k_loss(const float* __restrict__ pmax, const float* __restrict__ psum,
                       const float* __restrict__ tgt, float* __restrict__ out) {
  const int t = blockIdx.x;  // 0..510
  const int tid = threadIdx.x;
  const int lane = tid & 63;
  const int wv = tid >> 6;
  __shared__ float wmax[4], wsum[4];

  float pm = -3.4e38f, ps = 0.f;
  if (tid < 250) {
    pm = pmax[(tid << 9) + t];
    ps = psum[(tid << 9) + t];
  }
  float m = pm;
  UNROLL for (int mask = 1; mask < 64; mask <<= 1) m = fmaxf(m, __shfl_xor(m, mask, 64));
  if (lane == 0) wmax[wv] = m;
  __syncthreads();
  float M = fmaxf(fmaxf(wmax[0], wmax[1]), fmaxf(wmax[2], wmax[3]));
  float e = ps * __expf(pm - M);
  UNROLL for (int mask = 1; mask < 64; mask <<= 1) e += __shfl_xor(e, mask, 64);
  if (lane == 0) wsum[wv] = e;
  __syncthreads();
  if (tid == 0) out[t] = M + logf(wsum[0] + wsum[1] + wsum[2] + wsum[3]) - tgt[t];
}

extern "C" void kernel_launch(void* const* d_in, const int* in_sizes, int n_in,
                              void* d_out, int out_size, void* d_ws, size_t ws_size,
                              hipStream_t stream) {
  const int* source = (const int*)d_in[0];
  const int* target = (const int*)d_in[1];
  const float* enc_embed = (const float*)d_in[2];
  const float* enc_Wih = (const float*)d_in[3];
  const float* enc_Whh = (const float*)d_in[4];
  const float* enc_bih = (const float*)d_in[5];
  const float* enc_bhh = (const float*)d_in[6];
  const float* dec_embed = (const float*)d_in[7];
  const float* dec_Wih = (const float*)d_in[8];
  const float* dec_Whh = (const float*)d_in[9];
  const float* dec_bih = (const float*)d_in[10];
  const float* dec_bhh = (const float*)d_in[11];
  const float* W_out = (const float*)d_in[12];
  const float* b_out = (const float*)d_in[13];
  float* out = (float*)d_out;

  // Workspace map (non-overlapping, ~10.0 MB total):
  char* ws = (char*)d_ws;
  unsigned long long* hword = (unsigned long long*)(ws);  // 8192 u64 = 64 KB
  float* tgt = (float*)(ws + 65536);                      // 512 f32
  unsigned short* hsb = (unsigned short*)(ws + 67584);    // 512*512 bf16 = 512 KB
  float* pmax = (float*)(ws + 591872);                    // 250*512 f32 (stride 512)
  float* psum = (float*)(ws + 1116160);                   // 250*512 f32
  float* pre = (float*)(ws + 1640448);                    // 1023*2048 f32 = 8.38 MB

  k_pre<<<dim3(16, 8), 256, 0, stream>>>(source, target, enc_embed, enc_Wih, enc_bih, enc_bhh,
                                         dec_embed, dec_Wih, dec_bih, dec_bhh, pre, hword);
  k_lstm<<<64, 512, 0, stream>>>(enc_Whh, dec_Whh, pre, hword, hsb);
  k_logits<<<dim3(250, 4), 256, 0, stream>>>(hsb, W_out, b_out, target, pmax, psum, tgt);
  k_loss<<<511, 256, 0, stream>>>(pmax, psum, tgt, out);
}